// Round 23
// baseline (253.437 us; speedup 1.0000x reference)
//
#include <hip/hip_runtime.h>
#include <hip/hip_bf16.h>

typedef __attribute__((ext_vector_type(8))) short short8;
typedef __attribute__((ext_vector_type(16))) float f32x16;

__device__ __forceinline__ unsigned short f2bf(float f){
    unsigned u = __float_as_uint(f);
    unsigned r = (u + 0x7FFFu + ((u >> 16) & 1u)) >> 16;
    return (unsigned short)r;
}

// swizzled LDS byte offset, bijective XOR (row&15)<<4 (r14: conflicts 6.16M->786K)
__device__ __forceinline__ unsigned swz(unsigned row, unsigned byte_in_row, unsigned stride){
    return row * stride + (byte_in_row ^ ((row & 15u) << 4));
}

// ---- prep: transpose + bf16-convert weights ----
// W1T [256][128], W2T [128][256], W3T [512][256]  (all [n][k], bf16)
__global__ void prep_weights(const float* __restrict__ W1, const float* __restrict__ W2,
                             const float* __restrict__ W3,
                             unsigned short* __restrict__ W1T,
                             unsigned short* __restrict__ W2T,
                             unsigned short* __restrict__ W3T){
    int i = blockIdx.x * 256 + threadIdx.x;
    if (i < 32768){
        int n = i >> 7, k = i & 127;
        W1T[i] = f2bf(W1[k * 256 + n]);
    } else if (i < 65536){
        int j = i - 32768; int n = j >> 8, k = j & 255;
        W2T[j] = f2bf(W2[k * 128 + n]);
    } else if (i < 196608){
        int j = i - 65536; int n = j >> 8, k = j & 255;
        W3T[j] = f2bf(W3[k * 512 + n]);
    }
}

// ---- main: 64 tokens/block, 8 waves, 32x32x16 MFMA (swapped operands: D[n][token]) ----
// Why 32x32: halves the dominant LDS-read pipe (168 -> 96 ds_read_b128/wave; ~54us ->
// ~31us/CU serialized) at EQUAL register cost (acc f32x16 = 16 regs, same as 4x f32x4).
// Register law (r5..r21): <=64 VGPR -> 2 blk/CU (44% occ, 129us); >=84 -> 1 blk (23%).
// Layouts (measured, guide m74/m101): C/D col=lane&31 (token), row n = (reg&3)+8*(reg>>2)
// +4*(lane>>5); A/B frags: row/col = lane&31, k = (lane>>5)*8 + j.
__launch_bounds__(512, 2)
__global__ void main_kernel(const float* __restrict__ rho,
                            const float* __restrict__ c,
                            const float* __restrict__ w,
                            const int*  __restrict__ roads,
                            const unsigned short* __restrict__ W1T,
                            const float* __restrict__ b1,
                            const unsigned short* __restrict__ W2T,
                            const float* __restrict__ b2,
                            const unsigned short* __restrict__ W3T,
                            const float* __restrict__ b3,
                            const float* __restrict__ w21,
                            const float* __restrict__ b21s,
                            const float* __restrict__ w22,
                            const float* __restrict__ b22s,
                            float* __restrict__ pm,
                            float* __restrict__ pv)
{
    __shared__ __align__(16) unsigned char smem[65536];
    unsigned char* sXc  = smem;            // [64][128] bf16: gathered c, RECYCLED as c_t
    unsigned char* sH2  = smem + 16384;    // [64][256] bf16 f2 hidden (32KB); dead in GEMM3
    unsigned char* sRho = smem + 49152;    // [64][128] bf16 rho tile
    float* sPm = (float*)(smem + 16384);   // [8][32] head partials overlay sH2 (dead in GEMM3)
    float* sPv = (float*)(smem + 16384 + 2048);

    const int tid = threadIdx.x;
    const int t0  = blockIdx.x * 64;

    // stage: gather c rows (bf16) + rho tile (bf16)
    for (int u = tid; u < 64 * 32; u += 512){
        int row = u >> 5, ch = u & 31;
        int road = roads[t0 + row];
        float4 v = make_float4(0.f, 0.f, 0.f, 0.f);
        if (road > 0)
            v = reinterpret_cast<const float4*>(c + (size_t)(road - 1) * 128)[ch];
        ushort4 h;
        h.x = f2bf(v.x); h.y = f2bf(v.y); h.z = f2bf(v.z); h.w = f2bf(v.w);
        *reinterpret_cast<ushort4*>(sXc + swz(row, ch * 8, 256)) = h;

        float4 rv = reinterpret_cast<const float4*>(rho + (size_t)(t0 + row) * 128)[ch];
        ushort4 rh;
        rh.x = f2bf(rv.x); rh.y = f2bf(rv.y); rh.z = f2bf(rv.z); rh.w = f2bf(rv.w);
        *reinterpret_cast<ushort4*>(sRho + swz(row, ch * 8, 256)) = rh;
    }
    __syncthreads();

    const int lane = tid & 63, wv = tid >> 6;   // wv 0..7
    const int l31 = lane & 31, hi = lane >> 5;  // 32x32 frag coords

    // ---- GEMM1: H2 = selu(Xc @ W1 + b1), K=128, N=256; 2 passes ----
    // wave: token-tile mtA = wv&1; n-tile nt = (wv>>1) + 4p  (nt 0..7)
    {
        const int mtA = wv & 1;
        const int tok = mtA * 32 + l31;
        #pragma unroll 1
        for (int p = 0; p < 2; ++p){
            const int nt = (wv >> 1) + 4 * p;
            f32x16 acc = {};
            #pragma unroll
            for (int kk = 0; kk < 8; ++kk){     // K = 8 x 16
                short8 a = *reinterpret_cast<const short8*>(sXc + swz(tok, kk * 32 + hi * 16, 256));
                short8 b = *reinterpret_cast<const short8*>(W1T + (nt * 32 + l31) * 128 + kk * 16 + hi * 8);
                acc = __builtin_amdgcn_mfma_f32_32x32x16_bf16(b, a, acc, 0, 0, 0);
            }
            #pragma unroll
            for (int g = 0; g < 4; ++g){        // n-row groups {0,8,16,24} + hi*4
                const int nb = nt * 32 + g * 8 + hi * 4;
                float4 bb = *reinterpret_cast<const float4*>(b1 + nb);
                ushort4 h;
                #pragma unroll
                for (int j = 0; j < 4; ++j){
                    float vv = acc[g * 4 + j] + (&bb.x)[j];
                    vv = (vv > 0.f) ? 1.0507009873554805f * vv
                                    : 1.7580993408473766f * (__expf(vv) - 1.f);
                    reinterpret_cast<unsigned short*>(&h)[j] = f2bf(vv);
                }
                *reinterpret_cast<ushort4*>(sH2 + swz(tok, nb * 2, 512)) = h;
            }
        }
    }
    __syncthreads();

    // ---- GEMM2: c_t = H2 @ W2 + b2, K=256, N=128; 1 pass -> recycled sXc ----
    // wave: mtA = wv>>2; nt = wv&3
    {
        const int mtA = wv >> 2, nt = wv & 3;
        const int tok = mtA * 32 + l31;
        f32x16 acc = {};
        #pragma unroll
        for (int kk = 0; kk < 16; ++kk){        // K = 16 x 16
            short8 a = *reinterpret_cast<const short8*>(sH2 + swz(tok, kk * 32 + hi * 16, 512));
            short8 b = *reinterpret_cast<const short8*>(W2T + (nt * 32 + l31) * 256 + kk * 16 + hi * 8);
            acc = __builtin_amdgcn_mfma_f32_32x32x16_bf16(b, a, acc, 0, 0, 0);
        }
        #pragma unroll
        for (int g = 0; g < 4; ++g){
            const int nb = nt * 32 + g * 8 + hi * 4;
            float4 bb = *reinterpret_cast<const float4*>(b2 + nb);
            ushort4 h;
            #pragma unroll
            for (int j = 0; j < 4; ++j){
                float vv = acc[g * 4 + j] + (&bb.x)[j];
                reinterpret_cast<unsigned short*>(&h)[j] = f2bf(vv);
            }
            *reinterpret_cast<ushort4*>(sXc + swz(tok, nb * 2, 256)) = h;
        }
    }
    __syncthreads();

    // ---- GEMM3 + heads: h1 = relu([rho|c_t] @ W3 + b3); 4 passes ----
    // wave: mtA = wv&1 fixed (token-local heads!); nt = (wv>>1) + 4p (0..15)
    {
        const int mtA = wv & 1;
        const int tok = mtA * 32 + l31;
        float hm = 0.f, hv = 0.f;
        #pragma unroll 1
        for (int p = 0; p < 4; ++p){
            const int nt = (wv >> 1) + 4 * p;
            f32x16 acc = {};
            #pragma unroll
            for (int kk = 0; kk < 16; ++kk){    // K = 256: kk<8 rho, kk>=8 c_t
                const unsigned char* src = (kk < 8) ? sRho : sXc;
                short8 a = *reinterpret_cast<const short8*>(src + swz(tok, (kk & 7) * 32 + hi * 16, 256));
                short8 b = *reinterpret_cast<const short8*>(W3T + (nt * 32 + l31) * 256 + kk * 16 + hi * 8);
                acc = __builtin_amdgcn_mfma_f32_32x32x16_bf16(b, a, acc, 0, 0, 0);
            }
            #pragma unroll
            for (int g = 0; g < 4; ++g){
                const int nb = nt * 32 + g * 8 + hi * 4;
                float4 b3q = *reinterpret_cast<const float4*>(b3  + nb);
                float4 wmq = *reinterpret_cast<const float4*>(w21 + nb);
                float4 wvq = *reinterpret_cast<const float4*>(w22 + nb);
                #pragma unroll
                for (int j = 0; j < 4; ++j){
                    float h = fmaxf(acc[g * 4 + j] + (&b3q.x)[j], 0.f);
                    hm += h * (&wmq.x)[j];
                    hv += h * (&wvq.x)[j];
                }
            }
        }
        // lanes l and l+32 share token (different n-rows): pair-sum
        hm += __shfl_xor(hm, 32, 64);
        hv += __shfl_xor(hv, 32, 64);
        if (lane < 32){
            sPm[wv * 32 + l31] = hm;
            sPv[wv * 32 + l31] = hv;
        }
    }
    __syncthreads();
    // cross-wave reduce: waves {m, m+2, m+4, m+6} cover token-tile m
    if (tid < 64){
        const int m = tid >> 5, tk = tid & 31;
        float m_ = b21s[0], v_ = b22s[0];
        #pragma unroll
        for (int j = 0; j < 4; ++j){
            m_ += sPm[(m + 2 * j) * 32 + tk];
            v_ += sPv[(m + 2 * j) * 32 + tk];
        }
        int t = t0 + tid;
        float lw = logf(w[t]);
        pm[t] = m_ + lw;
        pv[t] = v_ + 2.f * lw;
    }
}

// ---- reduce: per-batch logsumexp + epilogue ----
__global__ void reduce_kernel(const float* __restrict__ pm, const float* __restrict__ pv,
                              const float* __restrict__ l, float* __restrict__ out){
    int b = blockIdx.x;
    int tid = threadIdx.x;
    const float* Pm = pm + (size_t)b * 2048;
    const float* Pv = pv + (size_t)b * 2048;

    float mm = -1e30f, mv = -1e30f;
    for (int i = tid; i < 2048; i += 256){
        mm = fmaxf(mm, Pm[i]);
        mv = fmaxf(mv, Pv[i]);
    }
    __shared__ float redm[4], redv[4];
    #pragma unroll
    for (int off = 32; off > 0; off >>= 1){
        mm = fmaxf(mm, __shfl_xor(mm, off, 64));
        mv = fmaxf(mv, __shfl_xor(mv, off, 64));
    }
    int wv = tid >> 6;
    if ((tid & 63) == 0){ redm[wv] = mm; redv[wv] = mv; }
    __syncthreads();
    mm = fmaxf(fmaxf(redm[0], redm[1]), fmaxf(redm[2], redm[3]));
    mv = fmaxf(fmaxf(redv[0], redv[1]), fmaxf(redv[2], redv[3]));

    float sm = 0.f, sv = 0.f;
    for (int i = tid; i < 2048; i += 256){
        sm += expf(Pm[i] - mm);
        sv += expf(Pv[i] - mv);
    }
    #pragma unroll
    for (int off = 32; off > 0; off >>= 1){
        sm += __shfl_xor(sm, off, 64);
        sv += __shfl_xor(sv, off, 64);
    }
    __shared__ float red2m[4], red2v[4];
    if ((tid & 63) == 0){ red2m[wv] = sm; red2v[wv] = sv; }
    __syncthreads();
    if (tid == 0){
        sm = red2m[0] + red2m[1] + red2m[2] + red2m[3];
        sv = red2v[0] + red2v[1] + red2v[2] + red2v[3];
        float lsem = mm + logf(sm);
        float lsev = mv + logf(sv);
        float ll = logf(l[b]);
        out[b]      = ll - lsem;
        out[64 + b] = ll - 3.f * lsem - lsev;
    }
}

extern "C" void kernel_launch(void* const* d_in, const int* in_sizes, int n_in,
                              void* d_out, int out_size, void* d_ws, size_t ws_size,
                              hipStream_t stream){
    const float* rho   = (const float*)d_in[0];
    const float* c     = (const float*)d_in[1];
    const float* w     = (const float*)d_in[2];
    const float* l     = (const float*)d_in[3];
    const int*   roads = (const int*)  d_in[4];
    const float* f2_W1 = (const float*)d_in[5];
    const float* f2_b1 = (const float*)d_in[6];
    const float* f2_W2 = (const float*)d_in[7];
    const float* f2_b2 = (const float*)d_in[8];
    const float* f_W1  = (const float*)d_in[9];
    const float* f_b1  = (const float*)d_in[10];
    const float* f_W21 = (const float*)d_in[11];
    const float* f_b21 = (const float*)d_in[12];
    const float* f_W22 = (const float*)d_in[13];
    const float* f_b22 = (const float*)d_in[14];

    unsigned char* ws = (unsigned char*)d_ws;
    unsigned short* W1T = (unsigned short*)(ws);                 // 65536 B
    unsigned short* W2T = (unsigned short*)(ws + 65536);         // 65536 B
    unsigned short* W3T = (unsigned short*)(ws + 131072);        // 262144 B
    float* pm = (float*)(ws + 393216);                           // 524288 B
    float* pv = (float*)(ws + 393216 + 524288);                  // 524288 B

    prep_weights<<<768, 256, 0, stream>>>(f2_W1, f2_W2, f_W1, W1T, W2T, W3T);
    main_kernel<<<2048, 512, 0, stream>>>(rho, c, w, roads,
                                          W1T, f2_b1, W2T, f2_b2, W3T, f_b1,
                                          f_W21, f_b21, f_W22, f_b22, pm, pv);
    reduce_kernel<<<64, 256, 0, stream>>>(pm, pv, l, (float*)d_out);
}

// Round 24
// 237.764 us; speedup vs baseline: 1.0659x; 1.0659x over previous
//
#include <hip/hip_runtime.h>
#include <hip/hip_bf16.h>

typedef __attribute__((ext_vector_type(8))) short short8;
typedef __attribute__((ext_vector_type(16))) float f32x16;

__device__ __forceinline__ unsigned short f2bf(float f){
    unsigned u = __float_as_uint(f);
    unsigned r = (u + 0x7FFFu + ((u >> 16) & 1u)) >> 16;
    return (unsigned short)r;
}

// swizzled LDS byte offset, bijective XOR (row&15)<<4 (r14: conflicts 6.16M->786K)
__device__ __forceinline__ unsigned swz(unsigned row, unsigned byte_in_row, unsigned stride){
    return row * stride + (byte_in_row ^ ((row & 15u) << 4));
}

// ---- prep: transpose + bf16-convert weights ----
// W1T [256][128], W2T [128][256], W3T [512][256]  (all [n][k], bf16)
__global__ void prep_weights(const float* __restrict__ W1, const float* __restrict__ W2,
                             const float* __restrict__ W3,
                             unsigned short* __restrict__ W1T,
                             unsigned short* __restrict__ W2T,
                             unsigned short* __restrict__ W3T){
    int i = blockIdx.x * 256 + threadIdx.x;
    if (i < 32768){
        int n = i >> 7, k = i & 127;
        W1T[i] = f2bf(W1[k * 256 + n]);
    } else if (i < 65536){
        int j = i - 32768; int n = j >> 8, k = j & 255;
        W2T[j] = f2bf(W2[k * 128 + n]);
    } else if (i < 196608){
        int j = i - 65536; int n = j >> 8, k = j & 255;
        W3T[j] = f2bf(W3[k * 512 + n]);
    }
}

// ---- main: 64 tokens/block, 8 waves, 32x32x16 MFMA, VGPR FORCED to 64 ----
// r23: this kernel at natural 72 VGPR -> 1 blk/CU (23.6%, 253us). The 2-blk boundary
// is 64<VGPR<=72 (r14: 60->44%). launch_bounds(512,4) caps at 2048/32=64 (r5 semantics).
// Only 8 regs over natural -> expect remat, not memory spills (r5's disaster was 124->64).
// Tripwire: WRITE_SIZE >> 1MB = spills -> revert to r14 (129us).
__launch_bounds__(512, 4)
__global__ void main_kernel(const float* __restrict__ rho,
                            const float* __restrict__ c,
                            const float* __restrict__ w,
                            const int*  __restrict__ roads,
                            const unsigned short* __restrict__ W1T,
                            const float* __restrict__ b1,
                            const unsigned short* __restrict__ W2T,
                            const float* __restrict__ b2,
                            const unsigned short* __restrict__ W3T,
                            const float* __restrict__ b3,
                            const float* __restrict__ w21,
                            const float* __restrict__ b21s,
                            const float* __restrict__ w22,
                            const float* __restrict__ b22s,
                            float* __restrict__ pm,
                            float* __restrict__ pv)
{
    __shared__ __align__(16) unsigned char smem[65536];
    unsigned char* sXc  = smem;            // [64][128] bf16: gathered c, RECYCLED as c_t
    unsigned char* sH2  = smem + 16384;    // [64][256] bf16 f2 hidden (32KB); dead in GEMM3
    unsigned char* sRho = smem + 49152;    // [64][128] bf16 rho tile
    float* sPm = (float*)(smem + 16384);   // [8][32] head partials overlay sH2 (dead in GEMM3)
    float* sPv = (float*)(smem + 16384 + 2048);

    const int tid = threadIdx.x;
    const int t0  = blockIdx.x * 64;

    // stage: gather c rows (bf16) + rho tile (bf16)
    for (int u = tid; u < 64 * 32; u += 512){
        int row = u >> 5, ch = u & 31;
        int road = roads[t0 + row];
        float4 v = make_float4(0.f, 0.f, 0.f, 0.f);
        if (road > 0)
            v = reinterpret_cast<const float4*>(c + (size_t)(road - 1) * 128)[ch];
        ushort4 h;
        h.x = f2bf(v.x); h.y = f2bf(v.y); h.z = f2bf(v.z); h.w = f2bf(v.w);
        *reinterpret_cast<ushort4*>(sXc + swz(row, ch * 8, 256)) = h;

        float4 rv = reinterpret_cast<const float4*>(rho + (size_t)(t0 + row) * 128)[ch];
        ushort4 rh;
        rh.x = f2bf(rv.x); rh.y = f2bf(rv.y); rh.z = f2bf(rv.z); rh.w = f2bf(rv.w);
        *reinterpret_cast<ushort4*>(sRho + swz(row, ch * 8, 256)) = rh;
    }
    __syncthreads();

    const int lane = tid & 63, wv = tid >> 6;   // wv 0..7
    const int l31 = lane & 31, hi = lane >> 5;  // 32x32 frag coords

    // ---- GEMM1: H2 = selu(Xc @ W1 + b1), K=128, N=256; 2 passes ----
    // wave: token-tile mtA = wv&1; n-tile nt = (wv>>1) + 4p  (nt 0..7)
    {
        const int mtA = wv & 1;
        const int tok = mtA * 32 + l31;
        #pragma unroll 1
        for (int p = 0; p < 2; ++p){
            const int nt = (wv >> 1) + 4 * p;
            f32x16 acc = {};
            #pragma unroll
            for (int kk = 0; kk < 8; ++kk){     // K = 8 x 16
                short8 a = *reinterpret_cast<const short8*>(sXc + swz(tok, kk * 32 + hi * 16, 256));
                short8 b = *reinterpret_cast<const short8*>(W1T + (nt * 32 + l31) * 128 + kk * 16 + hi * 8);
                acc = __builtin_amdgcn_mfma_f32_32x32x16_bf16(b, a, acc, 0, 0, 0);
            }
            #pragma unroll
            for (int g = 0; g < 4; ++g){        // n-row groups {0,8,16,24} + hi*4
                const int nb = nt * 32 + g * 8 + hi * 4;
                float4 bb = *reinterpret_cast<const float4*>(b1 + nb);
                ushort4 h;
                #pragma unroll
                for (int j = 0; j < 4; ++j){
                    float vv = acc[g * 4 + j] + (&bb.x)[j];
                    vv = (vv > 0.f) ? 1.0507009873554805f * vv
                                    : 1.7580993408473766f * (__expf(vv) - 1.f);
                    reinterpret_cast<unsigned short*>(&h)[j] = f2bf(vv);
                }
                *reinterpret_cast<ushort4*>(sH2 + swz(tok, nb * 2, 512)) = h;
            }
        }
    }
    __syncthreads();

    // ---- GEMM2: c_t = H2 @ W2 + b2, K=256, N=128; 1 pass -> recycled sXc ----
    // wave: mtA = wv>>2; nt = wv&3
    {
        const int mtA = wv >> 2, nt = wv & 3;
        const int tok = mtA * 32 + l31;
        f32x16 acc = {};
        #pragma unroll
        for (int kk = 0; kk < 16; ++kk){        // K = 16 x 16
            short8 a = *reinterpret_cast<const short8*>(sH2 + swz(tok, kk * 32 + hi * 16, 512));
            short8 b = *reinterpret_cast<const short8*>(W2T + (nt * 32 + l31) * 256 + kk * 16 + hi * 8);
            acc = __builtin_amdgcn_mfma_f32_32x32x16_bf16(b, a, acc, 0, 0, 0);
        }
        #pragma unroll
        for (int g = 0; g < 4; ++g){
            const int nb = nt * 32 + g * 8 + hi * 4;
            float4 bb = *reinterpret_cast<const float4*>(b2 + nb);
            ushort4 h;
            #pragma unroll
            for (int j = 0; j < 4; ++j){
                float vv = acc[g * 4 + j] + (&bb.x)[j];
                reinterpret_cast<unsigned short*>(&h)[j] = f2bf(vv);
            }
            *reinterpret_cast<ushort4*>(sXc + swz(tok, nb * 2, 256)) = h;
        }
    }
    __syncthreads();

    // ---- GEMM3 + heads: h1 = relu([rho|c_t] @ W3 + b3); 4 passes ----
    // wave: mtA = wv&1 fixed (token-local heads!); nt = (wv>>1) + 4p (0..15)
    {
        const int mtA = wv & 1;
        const int tok = mtA * 32 + l31;
        float hm = 0.f, hv = 0.f;
        #pragma unroll 1
        for (int p = 0; p < 4; ++p){
            const int nt = (wv >> 1) + 4 * p;
            f32x16 acc = {};
            #pragma unroll
            for (int kk = 0; kk < 16; ++kk){    // K = 256: kk<8 rho, kk>=8 c_t
                const unsigned char* src = (kk < 8) ? sRho : sXc;
                short8 a = *reinterpret_cast<const short8*>(src + swz(tok, (kk & 7) * 32 + hi * 16, 256));
                short8 b = *reinterpret_cast<const short8*>(W3T + (nt * 32 + l31) * 256 + kk * 16 + hi * 8);
                acc = __builtin_amdgcn_mfma_f32_32x32x16_bf16(b, a, acc, 0, 0, 0);
            }
            #pragma unroll
            for (int g = 0; g < 4; ++g){
                const int nb = nt * 32 + g * 8 + hi * 4;
                float4 b3q = *reinterpret_cast<const float4*>(b3  + nb);
                float4 wmq = *reinterpret_cast<const float4*>(w21 + nb);
                float4 wvq = *reinterpret_cast<const float4*>(w22 + nb);
                #pragma unroll
                for (int j = 0; j < 4; ++j){
                    float h = fmaxf(acc[g * 4 + j] + (&b3q.x)[j], 0.f);
                    hm += h * (&wmq.x)[j];
                    hv += h * (&wvq.x)[j];
                }
            }
        }
        // lanes l and l+32 share token (different n-rows): pair-sum
        hm += __shfl_xor(hm, 32, 64);
        hv += __shfl_xor(hv, 32, 64);
        if (lane < 32){
            sPm[wv * 32 + l31] = hm;
            sPv[wv * 32 + l31] = hv;
        }
    }
    __syncthreads();
    // cross-wave reduce: waves {m, m+2, m+4, m+6} cover token-tile m
    if (tid < 64){
        const int m = tid >> 5, tk = tid & 31;
        float m_ = b21s[0], v_ = b22s[0];
        #pragma unroll
        for (int j = 0; j < 4; ++j){
            m_ += sPm[(m + 2 * j) * 32 + tk];
            v_ += sPv[(m + 2 * j) * 32 + tk];
        }
        int t = t0 + tid;
        float lw = logf(w[t]);
        pm[t] = m_ + lw;
        pv[t] = v_ + 2.f * lw;
    }
}

// ---- reduce: per-batch logsumexp + epilogue ----
__global__ void reduce_kernel(const float* __restrict__ pm, const float* __restrict__ pv,
                              const float* __restrict__ l, float* __restrict__ out){
    int b = blockIdx.x;
    int tid = threadIdx.x;
    const float* Pm = pm + (size_t)b * 2048;
    const float* Pv = pv + (size_t)b * 2048;

    float mm = -1e30f, mv = -1e30f;
    for (int i = tid; i < 2048; i += 256){
        mm = fmaxf(mm, Pm[i]);
        mv = fmaxf(mv, Pv[i]);
    }
    __shared__ float redm[4], redv[4];
    #pragma unroll
    for (int off = 32; off > 0; off >>= 1){
        mm = fmaxf(mm, __shfl_xor(mm, off, 64));
        mv = fmaxf(mv, __shfl_xor(mv, off, 64));
    }
    int wv = tid >> 6;
    if ((tid & 63) == 0){ redm[wv] = mm; redv[wv] = mv; }
    __syncthreads();
    mm = fmaxf(fmaxf(redm[0], redm[1]), fmaxf(redm[2], redm[3]));
    mv = fmaxf(fmaxf(redv[0], redv[1]), fmaxf(redv[2], redv[3]));

    float sm = 0.f, sv = 0.f;
    for (int i = tid; i < 2048; i += 256){
        sm += expf(Pm[i] - mm);
        sv += expf(Pv[i] - mv);
    }
    #pragma unroll
    for (int off = 32; off > 0; off >>= 1){
        sm += __shfl_xor(sm, off, 64);
        sv += __shfl_xor(sv, off, 64);
    }
    __shared__ float red2m[4], red2v[4];
    if ((tid & 63) == 0){ red2m[wv] = sm; red2v[wv] = sv; }
    __syncthreads();
    if (tid == 0){
        sm = red2m[0] + red2m[1] + red2m[2] + red2m[3];
        sv = red2v[0] + red2v[1] + red2v[2] + red2v[3];
        float lsem = mm + logf(sm);
        float lsev = mv + logf(sv);
        float ll = logf(l[b]);
        out[b]      = ll - lsem;
        out[64 + b] = ll - 3.f * lsem - lsev;
    }
}

extern "C" void kernel_launch(void* const* d_in, const int* in_sizes, int n_in,
                              void* d_out, int out_size, void* d_ws, size_t ws_size,
                              hipStream_t stream){
    const float* rho   = (const float*)d_in[0];
    const float* c     = (const float*)d_in[1];
    const float* w     = (const float*)d_in[2];
    const float* l     = (const float*)d_in[3];
    const int*   roads = (const int*)  d_in[4];
    const float* f2_W1 = (const float*)d_in[5];
    const float* f2_b1 = (const float*)d_in[6];
    const float* f2_W2 = (const float*)d_in[7];
    const float* f2_b2 = (const float*)d_in[8];
    const float* f_W1  = (const float*)d_in[9];
    const float* f_b1  = (const float*)d_in[10];
    const float* f_W21 = (const float*)d_in[11];
    const float* f_b21 = (const float*)d_in[12];
    const float* f_W22 = (const float*)d_in[13];
    const float* f_b22 = (const float*)d_in[14];

    unsigned char* ws = (unsigned char*)d_ws;
    unsigned short* W1T = (unsigned short*)(ws);                 // 65536 B
    unsigned short* W2T = (unsigned short*)(ws + 65536);         // 65536 B
    unsigned short* W3T = (unsigned short*)(ws + 131072);        // 262144 B
    float* pm = (float*)(ws + 393216);                           // 524288 B
    float* pv = (float*)(ws + 393216 + 524288);                  // 524288 B

    prep_weights<<<768, 256, 0, stream>>>(f2_W1, f2_W2, f_W1, W1T, W2T, W3T);
    main_kernel<<<2048, 512, 0, stream>>>(rho, c, w, roads,
                                          W1T, f2_b1, W2T, f2_b2, W3T, f_b1,
                                          f_W21, f_b21, f_W22, f_b22, pm, pv);
    reduce_kernel<<<64, 256, 0, stream>>>(pm, pv, l, (float*)d_out);
}